// Round 1
// baseline (212.166 us; speedup 1.0000x reference)
//
#include <hip/hip_runtime.h>
#include <stdint.h>

#define B_ 8
#define T_ 1024
#define D_ 512
#define H_ 8
#define DK_ 64
#define M_ (B_*T_)

typedef unsigned short u16;
typedef __attribute__((ext_vector_type(8))) short bf16x8;
typedef __attribute__((ext_vector_type(4))) float f32x4;

static __device__ __forceinline__ u16 f2bf(float f) {
  union { float f; unsigned u; } v; v.f = f;
  unsigned r = (v.u + 0x7fffu + ((v.u >> 16) & 1u)) >> 16;
  return (u16)r;
}
static __device__ __forceinline__ float bf2f(u16 u) {
  union { unsigned u; float f; } v; v.u = ((unsigned)u) << 16;
  return v.f;
}
static __device__ __forceinline__ void async16(const u16* g, u16* l) {
  __builtin_amdgcn_global_load_lds(
      (const __attribute__((address_space(1))) void*)g,
      (__attribute__((address_space(3))) void*)l, 16, 0, 0);
}
static __device__ __forceinline__ f32x4 mfma16(bf16x8 a, bf16x8 b, f32x4 c) {
  return __builtin_amdgcn_mfma_f32_16x16x32_bf16(a, b, c, 0, 0, 0);
}

// ---------------- cast fp32 -> bf16 ----------------
__global__ void cast_k(const float* __restrict__ s, u16* __restrict__ d, int n) {
  int i = blockIdx.x * 256 + threadIdx.x;
  if (i < n) d[i] = f2bf(s[i]);
}

// ---------------- positional embedding ----------------
__global__ void posemb_k(const float* __restrict__ inp, u16* __restrict__ pe) {
  const int t = blockIdx.x, j = threadIdx.x;  // 256 threads
  float pos = inp[(size_t)t * D_];            // inputs[0, t, 0]
  float invf = expf(-(2.f * j / (float)D_) * 9.210340371976184f);  // 10000^-(2j/512)
  float ang = pos * invf;
  pe[(size_t)t * D_ + j] = f2bf(sinf(ang));
  pe[(size_t)t * D_ + 256 + j] = f2bf(cosf(ang));
}

// ---------------- fused double LayerNorm -> bf16 ----------------
__global__ __launch_bounds__(256)
void ln2_k(const float* __restrict__ x,
           const float* __restrict__ g1, const float* __restrict__ b1,
           const float* __restrict__ g2, const float* __restrict__ b2,
           u16* __restrict__ out) {
  __shared__ float red[16];
  const int row = blockIdx.x;
  const int t = threadIdx.x;
  const float2 v = *(const float2*)(x + (size_t)row * D_ + t * 2);

  float a = v.x + v.y;
  float b = v.x * v.x + v.y * v.y;
  for (int off = 32; off; off >>= 1) { a += __shfl_down(a, off, 64); b += __shfl_down(b, off, 64); }
  if ((t & 63) == 0) { red[t >> 6] = a; red[8 + (t >> 6)] = b; }
  __syncthreads();
  a = red[0] + red[1] + red[2] + red[3];
  b = red[8] + red[9] + red[10] + red[11];
  float mu = a * (1.f / D_);
  float var = b * (1.f / D_) - mu * mu;
  float rs = rsqrtf(var + 1e-5f);
  const float2 g1v = *(const float2*)(g1 + t * 2);
  const float2 b1v = *(const float2*)(b1 + t * 2);
  float y0 = (v.x - mu) * rs * g1v.x + b1v.x;
  float y1 = (v.y - mu) * rs * g1v.y + b1v.y;
  __syncthreads();  // protect red reuse
  a = y0 + y1;
  b = y0 * y0 + y1 * y1;
  for (int off = 32; off; off >>= 1) { a += __shfl_down(a, off, 64); b += __shfl_down(b, off, 64); }
  if ((t & 63) == 0) { red[t >> 6] = a; red[8 + (t >> 6)] = b; }
  __syncthreads();
  a = red[0] + red[1] + red[2] + red[3];
  b = red[8] + red[9] + red[10] + red[11];
  mu = a * (1.f / D_);
  var = b * (1.f / D_) - mu * mu;
  rs = rsqrtf(var + 1e-5f);
  const float2 g2v = *(const float2*)(g2 + t * 2);
  const float2 b2v = *(const float2*)(b2 + t * 2);
  u16* o = out + (size_t)row * D_ + t * 2;
  o[0] = f2bf((y0 - mu) * rs * g2v.x + b2v.x);
  o[1] = f2bf((y1 - mu) * rs * g2v.y + b2v.y);
}

// ---------------- bf16 GEMM: C = A(MxK) @ W(NxK)^T, templated epilogue ----------------
// MODE 0: qkv -> qu(+bu), qv(+bv), k, v  scattered to (B,H,T,DK)
// MODE 1: p -> (H,T,DK)
// MODE 2: out -> fp32 d_out + bias
template<int MODE>
__global__ __launch_bounds__(256, 2)
void gemm_k(const u16* __restrict__ A, const u16* __restrict__ Bw,
            int M, int N, int K,
            u16* __restrict__ o0, u16* __restrict__ o1,
            u16* __restrict__ o2, u16* __restrict__ o3,
            float* __restrict__ fo,
            const float* __restrict__ bu, const float* __restrict__ bv,
            const float* __restrict__ bo) {
  __shared__ u16 As[2][128 * 32];
  __shared__ u16 Bs[2][128 * 32];
  const int tid = threadIdx.x;
  const int l = tid & 63, w = tid >> 6;
  const int m0 = blockIdx.x * 128, n0 = blockIdx.y * 128;
  const int wm = (w >> 1) * 64, wn = (w & 1) * 64;
  const int nk = K >> 5;

  auto stage = [&](int bufi, int kt) {
    const u16* ga = A + (size_t)(m0 + (tid >> 2)) * K + kt * 32 + (tid & 3) * 8;
    u16* la = &As[bufi][tid * 8];
    async16(ga, la);
    async16(ga + (size_t)64 * K, la + 64 * 32);
    const u16* gb = Bw + (size_t)(n0 + (tid >> 2)) * K + kt * 32 + (tid & 3) * 8;
    u16* lb = &Bs[bufi][tid * 8];
    async16(gb, lb);
    async16(gb + (size_t)64 * K, lb + 64 * 32);
  };

  f32x4 acc[4][4] = {};
  stage(0, 0);
  for (int kt = 0; kt < nk; ++kt) {
    __syncthreads();               // buf[kt&1] staged (vmcnt drained) + prev compute done
    if (kt + 1 < nk) stage((kt + 1) & 1, kt + 1);
    const u16* as = As[kt & 1];
    const u16* bs = Bs[kt & 1];
    bf16x8 af[4], bfr[4];
#pragma unroll
    for (int i = 0; i < 4; ++i)
      af[i] = *(const bf16x8*)&as[(wm + i * 16 + (l & 15)) * 32 + (l >> 4) * 8];
#pragma unroll
    for (int j = 0; j < 4; ++j)
      bfr[j] = *(const bf16x8*)&bs[(wn + j * 16 + (l & 15)) * 32 + (l >> 4) * 8];
#pragma unroll
    for (int i = 0; i < 4; ++i)
#pragma unroll
      for (int j = 0; j < 4; ++j)
        acc[i][j] = mfma16(af[i], bfr[j], acc[i][j]);
  }

#pragma unroll
  for (int i = 0; i < 4; ++i)
#pragma unroll
    for (int j = 0; j < 4; ++j)
#pragma unroll
      for (int r = 0; r < 4; ++r) {
        int row = m0 + wm + i * 16 + ((l >> 4) << 2) + r;
        int col = n0 + wn + j * 16 + (l & 15);
        float val = acc[i][j][r];
        if (MODE == 0) {
          int b = row >> 10, t = row & 1023;
          int sec = col >> 9, cc = col & 511;
          int h = cc >> 6, dk = cc & 63;
          size_t idx = ((size_t)(b * H_ + h) * T_ + t) * DK_ + dk;
          if (sec == 0) {
            o0[idx] = f2bf(val + bu[cc]);
            o1[idx] = f2bf(val + bv[cc]);
          } else if (sec == 1) {
            o2[idx] = f2bf(val);
          } else {
            o3[idx] = f2bf(val);
          }
        } else if (MODE == 1) {
          int h = col >> 6, dk = col & 63;
          o0[(size_t)(h * T_ + row) * DK_ + dk] = f2bf(val);
        } else {
          fo[(size_t)row * D_ + col] = val + bo[col];
        }
      }
}

// ---------------- V transpose: (B,H,T,DK) -> (B,H,DK,T) ----------------
__global__ __launch_bounds__(256)
void trv_k(const u16* __restrict__ v, u16* __restrict__ vt) {
  __shared__ u16 tl[64 * 72];
  const int tid = threadIdx.x;
  const int bh = blockIdx.y;
  const int t0 = blockIdx.x * 64;
  const u16* src = v + ((size_t)bh * T_ + t0) * DK_;
#pragma unroll
  for (int i = 0; i < 2; ++i) {
    int r = i * 32 + (tid >> 3), c = (tid & 7) * 8;
    *(uint4*)&tl[r * 72 + c] = *(const uint4*)&src[(size_t)r * 64 + c];
  }
  __syncthreads();
  const int dk = tid >> 2, tj = (tid & 3) * 16;
  u16 tmp[16] __attribute__((aligned(16)));
#pragma unroll
  for (int jj = 0; jj < 16; ++jj) tmp[jj] = tl[(tj + jj) * 72 + dk];
  u16* dst = vt + ((size_t)bh * DK_ + dk) * T_ + t0 + tj;
  *(uint4*)&dst[0] = *(const uint4*)&tmp[0];
  *(uint4*)&dst[8] = *(const uint4*)&tmp[8];
}

// ---------------- fused rel-attention (flash, per (b,h, 64 q-rows)) ----------------
__global__ __launch_bounds__(256, 2)
void attn_k(const u16* __restrict__ qu, const u16* __restrict__ qv,
            const u16* __restrict__ kb, const u16* __restrict__ vt,
            const u16* __restrict__ pb, u16* __restrict__ ao) {
  __shared__ u16 k_lds[64 * 64];
  __shared__ u16 v_lds[64 * 64];
  __shared__ u16 pl_lds[128 * 64];
  __shared__ u16 pu_lds[128 * 64];
  __shared__ u16 scr[4][16 * 88];   // per-wave: band (stride 84) then P (stride 72)

  const int tid = threadIdx.x;
  const int l = tid & 63, w = tid >> 6;
  const int qb = blockIdx.x, q0 = qb * 64;
  const int bh = blockIdx.y;
  const int b = bh >> 3, h = bh & 7;

  const u16* quB = qu + (size_t)bh * T_ * DK_;
  const u16* qvB = qv + (size_t)bh * T_ * DK_;
  const u16* kB  = kb + (size_t)bh * T_ * DK_;
  const u16* vB  = vt + (size_t)bh * DK_ * T_;
  const u16* pB  = pb + (size_t)h * T_ * DK_;

  // q fragments for this wave's 16 rows (A operand: row = l&15, k = (l>>4)*8..)
  bf16x8 quf[2], qvf[2], qsf[2];
  {
    const int row = q0 + w * 16 + (l & 15);
    const int ko = (l >> 4) * 8;
    const u16* a0 = quB + (size_t)row * DK_ + ko;
    quf[0] = *(const bf16x8*)a0;
    quf[1] = *(const bf16x8*)(a0 + 32);
    const u16* a1 = qvB + (size_t)row * DK_ + ko;
    qvf[0] = *(const bf16x8*)a1;
    qvf[1] = *(const bf16x8*)(a1 + 32);
    const int row2 = (row + 1 < T_) ? row + 1 : T_ - 1;
    const u16* a2 = qvB + (size_t)row2 * DK_ + ko;  // shifted qv rows (q+1)
    qsf[0] = *(const bf16x8*)a2;
    qsf[1] = *(const bf16x8*)(a2 + 32);
  }

  f32x4 o[4] = {};
  float mrun[4], lrun[4];
#pragma unroll
  for (int r = 0; r < 4; ++r) { mrun[r] = -1e30f; lrun[r] = 0.f; }

  const int rbase = 48 - w * 16;  // wave's row offset into staged p band
  u16* bandw = &scr[w][0];

  for (int kt = 0; kt < 16; ++kt) {
    const int k0 = kt * 64;
    const bool needL = (kt <= qb);
    const bool needU = (kt >= qb);

    __syncthreads();  // prev compute done before overwriting tiles
    {  // K tile: 64 t-rows x 64 dk
      const u16* g = kB + (size_t)(k0 + (tid >> 3)) * DK_ + (tid & 7) * 8;
      u16* s = &k_lds[tid * 8];
      async16(g, s);
      async16(g + 32 * DK_, s + 32 * 64);
    }
    {  // V^T tile: 64 dk-rows x 64 t
      const u16* g = vB + (size_t)(tid >> 3) * T_ + k0 + (tid & 7) * 8;
      u16* s = &v_lds[tid * 8];
      async16(g, s);
      async16(g + 32 * T_, s + 32 * 64);
    }
    if (needL) {
      const int jb = T_ - 64 + k0 - q0;
#pragma unroll
      for (int i = 0; i < 4; ++i) {
        int rr = i * 32 + (tid >> 3);
        int j = jb + rr; j = j < 0 ? 0 : (j > T_ - 1 ? T_ - 1 : j);
        async16(pB + (size_t)j * DK_ + (tid & 7) * 8, &pl_lds[rr * 64 + (tid & 7) * 8]);
      }
    }
    if (needU) {
      const int jb = k0 - q0 - 65;
#pragma unroll
      for (int i = 0; i < 4; ++i) {
        int rr = i * 32 + (tid >> 3);
        int j = jb + rr; j = j < 0 ? 0 : (j > T_ - 1 ? T_ - 1 : j);
        async16(pB + (size_t)j * DK_ + (tid & 7) * 8, &pu_lds[rr * 64 + (tid & 7) * 8]);
      }
    }
    __syncthreads();  // staging complete

    // ac = qu . k^T
    float sv[4][4];
#pragma unroll
    for (int nf = 0; nf < 4; ++nf) {
      const u16* kbase = &k_lds[(nf * 16 + (l & 15)) * 64 + (l >> 4) * 8];
      bf16x8 b0 = *(const bf16x8*)kbase;
      bf16x8 b1 = *(const bf16x8*)(kbase + 32);
      f32x4 acs = {};
      acs = mfma16(quf[0], b0, acs);
      acs = mfma16(quf[1], b1, acs);
#pragma unroll
      for (int r = 0; r < 4; ++r) sv[nf][r] = acs[r];
    }

    // lower band: bd[q,k] = qv[q].p[T-1+k-q]  (k<=q); u = kcol-qrow+15
    if (needL) {
#pragma unroll
      for (int fu = 0; fu < 5; ++fu) {
        const u16* pbase = &pl_lds[(rbase + fu * 16 + (l & 15)) * 64 + (l >> 4) * 8];
        bf16x8 p0 = *(const bf16x8*)pbase;
        bf16x8 p1 = *(const bf16x8*)(pbase + 32);
        f32x4 c = {};
        c = mfma16(qvf[0], p0, c);
        c = mfma16(qvf[1], p1, c);
#pragma unroll
        for (int r = 0; r < 4; ++r)
          bandw[((l >> 4) * 4 + r) * 84 + fu * 16 + (l & 15)] = f2bf(c[r]);
      }
#pragma unroll
      for (int nf = 0; nf < 4; ++nf)
#pragma unroll
        for (int r = 0; r < 4; ++r) {
          int qrow = (l >> 4) * 4 + r;
          int kcol = nf * 16 + (l & 15);
          int rel = (k0 + kcol) - (q0 + w * 16 + qrow);
          if (rel <= 0) sv[nf][r] += bf2f(bandw[qrow * 84 + kcol - qrow + 15]);
        }
    }
    // upper band: bd[q,k] = qv[q+1].p[k-q-2]  (k>=q+2); bd=0 at k=q+1
    if (needU) {
#pragma unroll
      for (int fu = 0; fu < 5; ++fu) {
        const u16* pbase = &pu_lds[(rbase + fu * 16 + (l & 15)) * 64 + (l >> 4) * 8];
        bf16x8 p0 = *(const bf16x8*)pbase;
        bf16x8 p1 = *(const bf16x8*)(pbase + 32);
        f32x4 c = {};
        c = mfma16(qsf[0], p0, c);
        c = mfma16(qsf[1], p1, c);
#pragma unroll
        for (int r = 0; r < 4; ++r)
          bandw[((l >> 4) * 4 + r) * 84 + fu * 16 + (l & 15)] = f2bf(c[r]);
      }
#pragma unroll
      for (int nf = 0; nf < 4; ++nf)
#pragma unroll
        for (int r = 0; r < 4; ++r) {
          int qrow = (l >> 4) * 4 + r;
          int kcol = nf * 16 + (l & 15);
          int rel = (k0 + kcol) - (q0 + w * 16 + qrow);
          if (rel >= 2) sv[nf][r] += bf2f(bandw[qrow * 84 + kcol - qrow + 15]);
        }
    }

#pragma unroll
    for (int nf = 0; nf < 4; ++nf)
#pragma unroll
      for (int r = 0; r < 4; ++r) sv[nf][r] *= 0.125f;  // 1/sqrt(DK)

    // online softmax
    float mnew[4], scl[4];
#pragma unroll
    for (int r = 0; r < 4; ++r) {
      float mx = fmaxf(fmaxf(sv[0][r], sv[1][r]), fmaxf(sv[2][r], sv[3][r]));
#pragma unroll
      for (int off = 1; off < 16; off <<= 1) mx = fmaxf(mx, __shfl_xor(mx, off, 64));
      mnew[r] = fmaxf(mrun[r], mx);
      scl[r] = __expf(mrun[r] - mnew[r]);
      mrun[r] = mnew[r];
    }
#pragma unroll
    for (int r = 0; r < 4; ++r) {
      float s0 = 0.f;
#pragma unroll
      for (int nf = 0; nf < 4; ++nf) {
        float p = __expf(sv[nf][r] - mnew[r]);
        sv[nf][r] = p;
        s0 += p;
      }
#pragma unroll
      for (int off = 1; off < 16; off <<= 1) s0 += __shfl_xor(s0, off, 64);
      lrun[r] = lrun[r] * scl[r] + s0;
    }
#pragma unroll
    for (int df = 0; df < 4; ++df)
#pragma unroll
      for (int r = 0; r < 4; ++r) o[df][r] *= scl[r];

    // P -> LDS (bf16), re-read as A fragments
#pragma unroll
    for (int nf = 0; nf < 4; ++nf)
#pragma unroll
      for (int r = 0; r < 4; ++r)
        bandw[((l >> 4) * 4 + r) * 72 + nf * 16 + (l & 15)] = f2bf(sv[nf][r]);

    bf16x8 pa0 = *(const bf16x8*)&bandw[(l & 15) * 72 + (l >> 4) * 8];
    bf16x8 pa1 = *(const bf16x8*)&bandw[(l & 15) * 72 + 32 + (l >> 4) * 8];
#pragma unroll
    for (int df = 0; df < 4; ++df) {
      const u16* vb2 = &v_lds[(df * 16 + (l & 15)) * 64 + (l >> 4) * 8];
      bf16x8 v0 = *(const bf16x8*)vb2;
      bf16x8 v1 = *(const bf16x8*)(vb2 + 32);
      o[df] = mfma16(pa0, v0, o[df]);
      o[df] = mfma16(pa1, v1, o[df]);
    }
  }

#pragma unroll
  for (int df = 0; df < 4; ++df)
#pragma unroll
    for (int r = 0; r < 4; ++r) {
      int q = q0 + w * 16 + (l >> 4) * 4 + r;
      int dk = df * 16 + (l & 15);
      float val = o[df][r] / lrun[r];
      ao[((size_t)b * T_ + q) * D_ + h * DK_ + dk] = f2bf(val);
    }
}

extern "C" void kernel_launch(void* const* d_in, const int* in_sizes, int n_in,
                              void* d_out, int out_size, void* d_ws, size_t ws_size,
                              hipStream_t stream) {
  const float* inputs = (const float*)d_in[0];
  const float* ln1_g = (const float*)d_in[1];
  const float* ln1_b = (const float*)d_in[2];
  const float* ln2_g = (const float*)d_in[3];
  const float* ln2_b = (const float*)d_in[4];
  const float* W_qkv = (const float*)d_in[5];
  const float* W_pos = (const float*)d_in[6];
  const float* W_out = (const float*)d_in[7];
  const float* b_out = (const float*)d_in[8];
  const float* pbu = (const float*)d_in[9];
  const float* pbv = (const float*)d_in[10];
  float* out = (float*)d_out;

  char* ws = (char*)d_ws;
  size_t off = 0;
  auto alloc = [&](size_t bytes) {
    char* p = ws + off;
    off += (bytes + 255) & ~(size_t)255;
    return p;
  };
  u16* xn   = (u16*)alloc((size_t)M_ * D_ * 2);
  u16* wqkv = (u16*)alloc((size_t)3 * D_ * D_ * 2);
  u16* wpos = (u16*)alloc((size_t)D_ * D_ * 2);
  u16* wout = (u16*)alloc((size_t)D_ * D_ * 2);
  u16* pemb = (u16*)alloc((size_t)T_ * D_ * 2);
  u16* quB  = (u16*)alloc((size_t)M_ * D_ * 2);
  u16* qvB  = (u16*)alloc((size_t)M_ * D_ * 2);
  u16* kbB  = (u16*)alloc((size_t)M_ * D_ * 2);
  u16* vbB  = (u16*)alloc((size_t)M_ * D_ * 2);
  u16* vtB  = (u16*)alloc((size_t)M_ * D_ * 2);
  u16* pbuf = (u16*)alloc((size_t)H_ * T_ * DK_ * 2);
  u16* aoB  = (u16*)alloc((size_t)M_ * D_ * 2);
  if (ws_size < off) return;  // insufficient scratch -> visible validation failure

  cast_k<<<(3 * D_ * D_ + 255) / 256, 256, 0, stream>>>(W_qkv, wqkv, 3 * D_ * D_);
  cast_k<<<(D_ * D_ + 255) / 256, 256, 0, stream>>>(W_pos, wpos, D_ * D_);
  cast_k<<<(D_ * D_ + 255) / 256, 256, 0, stream>>>(W_out, wout, D_ * D_);
  posemb_k<<<T_, 256, 0, stream>>>(inputs, pemb);
  ln2_k<<<M_, 256, 0, stream>>>(inputs, ln1_g, ln1_b, ln2_g, ln2_b, xn);

  gemm_k<1><<<dim3(T_ / 128, D_ / 128), 256, 0, stream>>>(
      pemb, wpos, T_, D_, D_, pbuf, nullptr, nullptr, nullptr, nullptr,
      nullptr, nullptr, nullptr);
  gemm_k<0><<<dim3(M_ / 128, (3 * D_) / 128), 256, 0, stream>>>(
      xn, wqkv, M_, 3 * D_, D_, quB, qvB, kbB, vbB, nullptr, pbu, pbv, nullptr);
  trv_k<<<dim3(T_ / 64, B_ * H_), 256, 0, stream>>>(vbB, vtB);
  attn_k<<<dim3(T_ / 64, B_ * H_), 256, 0, stream>>>(quB, qvB, kbB, vtB, pbuf, aoB);
  gemm_k<2><<<dim3(M_ / 128, D_ / 128), 256, 0, stream>>>(
      aoB, wout, M_, D_, D_, nullptr, nullptr, nullptr, nullptr, out,
      nullptr, nullptr, b_out);
}

// Round 2
// 179.875 us; speedup vs baseline: 1.1795x; 1.1795x over previous
//
#include <hip/hip_runtime.h>
#include <stdint.h>

#define B_ 8
#define T_ 1024
#define D_ 512
#define H_ 8
#define DK_ 64
#define M_ (B_*T_)

typedef unsigned short u16;
typedef __attribute__((ext_vector_type(8))) short bf16x8;
typedef __attribute__((ext_vector_type(4))) float f32x4;

static __device__ __forceinline__ u16 f2bf(float f) {
  union { float f; unsigned u; } v; v.f = f;
  unsigned r = (v.u + 0x7fffu + ((v.u >> 16) & 1u)) >> 16;
  return (u16)r;
}
static __device__ __forceinline__ float bf2f(u16 u) {
  union { unsigned u; float f; } v; v.u = ((unsigned)u) << 16;
  return v.f;
}
static __device__ __forceinline__ void async16(const u16* g, u16* l) {
  __builtin_amdgcn_global_load_lds(
      (const __attribute__((address_space(1))) void*)g,
      (__attribute__((address_space(3))) void*)l, 16, 0, 0);
}
static __device__ __forceinline__ f32x4 mfma16(bf16x8 a, bf16x8 b, f32x4 c) {
  return __builtin_amdgcn_mfma_f32_16x16x32_bf16(a, b, c, 0, 0, 0);
}

// ---------------- merged weight casts fp32 -> bf16 ----------------
__global__ void cast3_k(const float* __restrict__ a, const float* __restrict__ b,
                        const float* __restrict__ c, u16* __restrict__ da,
                        u16* __restrict__ db, u16* __restrict__ dc) {
  const int na = 3 * D_ * D_ / 4, nb = D_ * D_ / 4;
  int i = blockIdx.x * 256 + threadIdx.x;
  const float* s; u16* d; int j;
  if (i < na) { s = a; d = da; j = i; }
  else if (i < na + nb) { s = b; d = db; j = i - na; }
  else { s = c; d = dc; j = i - na - nb; }
  float4 v = ((const float4*)s)[j];
  ushort4 o;
  o.x = f2bf(v.x); o.y = f2bf(v.y); o.z = f2bf(v.z); o.w = f2bf(v.w);
  ((ushort4*)d)[j] = o;
}

// ---------------- positional embedding ----------------
__global__ void posemb_k(const float* __restrict__ inp, u16* __restrict__ pe) {
  const int t = blockIdx.x, j = threadIdx.x;  // 256 threads
  float pos = inp[(size_t)t * D_];            // inputs[0, t, 0]
  float invf = expf(-(2.f * j / (float)D_) * 9.210340371976184f);
  float ang = pos * invf;
  pe[(size_t)t * D_ + j] = f2bf(sinf(ang));
  pe[(size_t)t * D_ + 256 + j] = f2bf(cosf(ang));
}

// ---------------- fused double LayerNorm -> bf16 ----------------
__global__ __launch_bounds__(256)
void ln2_k(const float* __restrict__ x,
           const float* __restrict__ g1, const float* __restrict__ b1,
           const float* __restrict__ g2, const float* __restrict__ b2,
           u16* __restrict__ out) {
  __shared__ float red[16];
  const int row = blockIdx.x;
  const int t = threadIdx.x;
  const float2 v = *(const float2*)(x + (size_t)row * D_ + t * 2);

  float a = v.x + v.y;
  float b = v.x * v.x + v.y * v.y;
  for (int off = 32; off; off >>= 1) { a += __shfl_down(a, off, 64); b += __shfl_down(b, off, 64); }
  if ((t & 63) == 0) { red[t >> 6] = a; red[8 + (t >> 6)] = b; }
  __syncthreads();
  a = red[0] + red[1] + red[2] + red[3];
  b = red[8] + red[9] + red[10] + red[11];
  float mu = a * (1.f / D_);
  float var = b * (1.f / D_) - mu * mu;
  float rs = rsqrtf(var + 1e-5f);
  const float2 g1v = *(const float2*)(g1 + t * 2);
  const float2 b1v = *(const float2*)(b1 + t * 2);
  float y0 = (v.x - mu) * rs * g1v.x + b1v.x;
  float y1 = (v.y - mu) * rs * g1v.y + b1v.y;
  __syncthreads();
  a = y0 + y1;
  b = y0 * y0 + y1 * y1;
  for (int off = 32; off; off >>= 1) { a += __shfl_down(a, off, 64); b += __shfl_down(b, off, 64); }
  if ((t & 63) == 0) { red[t >> 6] = a; red[8 + (t >> 6)] = b; }
  __syncthreads();
  a = red[0] + red[1] + red[2] + red[3];
  b = red[8] + red[9] + red[10] + red[11];
  mu = a * (1.f / D_);
  var = b * (1.f / D_) - mu * mu;
  rs = rsqrtf(var + 1e-5f);
  const float2 g2v = *(const float2*)(g2 + t * 2);
  const float2 b2v = *(const float2*)(b2 + t * 2);
  u16* o = out + (size_t)row * D_ + t * 2;
  o[0] = f2bf((y0 - mu) * rs * g2v.x + b2v.x);
  o[1] = f2bf((y1 - mu) * rs * g2v.y + b2v.y);
}

// ---------------- bf16 GEMM: C = A(MxK) @ W(NxK)^T, templated epilogue ----------------
// MODE 0: qkv -> q (bf16 BHTD), k (BHTD), v transposed (BHDT)
// MODE 1: p -> (H,T,DK)
// MODE 2: out -> fp32 d_out + bias
template<int MODE>
__global__ __launch_bounds__(256, 2)
void gemm_k(const u16* __restrict__ A, const u16* __restrict__ Bw,
            int M, int N, int K,
            u16* __restrict__ o0, u16* __restrict__ o1, u16* __restrict__ o2,
            float* __restrict__ fo, const float* __restrict__ bo) {
  __shared__ u16 As[2][128 * 32];
  __shared__ u16 Bs[2][128 * 32];
  const int tid = threadIdx.x;
  const int l = tid & 63, w = tid >> 6;
  const int m0 = blockIdx.x * 128, n0 = blockIdx.y * 128;
  const int wm = (w >> 1) * 64, wn = (w & 1) * 64;
  const int nk = K >> 5;

  auto stage = [&](int bufi, int kt) {
    const int row = tid >> 2;
    const int cg = ((tid & 3) ^ ((row + (row >> 2)) & 3)) * 8;  // 64B-row swizzle
    const u16* ga = A + (size_t)(m0 + row) * K + kt * 32 + cg;
    u16* la = &As[bufi][tid * 8];
    async16(ga, la);
    async16(ga + (size_t)64 * K, la + 64 * 32);
    const u16* gb = Bw + (size_t)(n0 + row) * K + kt * 32 + cg;
    u16* lb = &Bs[bufi][tid * 8];
    async16(gb, lb);
    async16(gb + (size_t)64 * K, lb + 64 * 32);
  };

  // per-lane swizzled chunk offset (row&3 == l&3 for 16-aligned row bases)
  const int fl = (((l & 15) + ((l & 15) >> 2)) & 3);
  const int coff = ((l >> 4) ^ fl) * 8;
  const int aoff = (l & 15) * 32 + coff;

  f32x4 acc[4][4] = {};
  stage(0, 0);
  for (int kt = 0; kt < nk; ++kt) {
    __syncthreads();
    if (kt + 1 < nk) stage((kt + 1) & 1, kt + 1);
    const u16* as = As[kt & 1];
    const u16* bs = Bs[kt & 1];
    bf16x8 af[4], bfr[4];
#pragma unroll
    for (int i = 0; i < 4; ++i)
      af[i] = *(const bf16x8*)&as[(wm + i * 16) * 32 + aoff];
#pragma unroll
    for (int j = 0; j < 4; ++j)
      bfr[j] = *(const bf16x8*)&bs[(wn + j * 16) * 32 + aoff];
#pragma unroll
    for (int i = 0; i < 4; ++i)
#pragma unroll
      for (int j = 0; j < 4; ++j)
        acc[i][j] = mfma16(af[i], bfr[j], acc[i][j]);
  }

#pragma unroll
  for (int i = 0; i < 4; ++i)
#pragma unroll
    for (int j = 0; j < 4; ++j) {
      const int row0 = m0 + wm + i * 16 + ((l >> 4) << 2);
      const int col = n0 + wn + j * 16 + (l & 15);
      if (MODE == 0) {
        const int sec = col >> 9, cc = col & 511;
        const int hh = cc >> 6, dk = cc & 63;
        const int bb = row0 >> 10, t0r = row0 & 1023;
        if (sec == 2) {  // V, transposed store (B,H,DK,T)
          ushort4 v4;
          v4.x = f2bf(acc[i][j][0]); v4.y = f2bf(acc[i][j][1]);
          v4.z = f2bf(acc[i][j][2]); v4.w = f2bf(acc[i][j][3]);
          *(ushort4*)&o2[((size_t)(bb * H_ + hh) * DK_ + dk) * T_ + t0r] = v4;
        } else {
          u16* dst = (sec == 0) ? o0 : o1;
#pragma unroll
          for (int r = 0; r < 4; ++r)
            dst[((size_t)(bb * H_ + hh) * T_ + t0r + r) * DK_ + dk] = f2bf(acc[i][j][r]);
        }
      } else if (MODE == 1) {
        const int hh = col >> 6, dk = col & 63;
#pragma unroll
        for (int r = 0; r < 4; ++r)
          o0[((size_t)hh * T_ + row0 + r) * DK_ + dk] = f2bf(acc[i][j][r]);
      } else {
#pragma unroll
        for (int r = 0; r < 4; ++r)
          fo[(size_t)(row0 + r) * D_ + col] = acc[i][j][r] + bo[col];
      }
    }
}

// ---------------- fused rel-attention (flash, per (b,h, 64 q-rows)) ----------------
__global__ __launch_bounds__(256, 3)
void attn_k(const u16* __restrict__ q, const u16* __restrict__ kb,
            const u16* __restrict__ vt, const u16* __restrict__ pb,
            const float* __restrict__ bu, const float* __restrict__ bv,
            u16* __restrict__ ao) {
  __shared__ u16 k_lds[64 * 64];
  __shared__ u16 v_lds[64 * 64];
  __shared__ u16 p_lds[128 * 64];
  __shared__ u16 scr[4][16 * 84];  // per-wave: band (stride 84) / P (stride 72)

  const int tid = threadIdx.x;
  const int l = tid & 63, w = tid >> 6;
  // XCD-locality remap: all 16 q-blocks of a bh land on one XCD (d%8 const)
  const int dd = blockIdx.x;
  const int bh = (dd & 7) * 8 + (dd >> 7);
  const int qb = (dd >> 3) & 15;
  const int q0 = qb * 64;
  const int b = bh >> 3, h = bh & 7;

  const u16* qB = q + (size_t)bh * T_ * DK_;
  const u16* kB = kb + (size_t)bh * T_ * DK_;
  const u16* vB = vt + (size_t)bh * DK_ * T_;
  const u16* pB = pb + (size_t)h * T_ * DK_;

  // q fragments + positional biases in-register
  bf16x8 quf[2], qvf[2], qsf[2];
  {
    const float* buH = bu + h * DK_;
    const float* bvH = bv + h * DK_;
    const int row = q0 + w * 16 + (l & 15);
    const int row2 = (row + 1 < T_) ? row + 1 : T_ - 1;
    const int ko = (l >> 4) * 8;
    const bf16x8 qa0 = *(const bf16x8*)(qB + (size_t)row * DK_ + ko);
    const bf16x8 qa1 = *(const bf16x8*)(qB + (size_t)row * DK_ + ko + 32);
    const bf16x8 qs0 = *(const bf16x8*)(qB + (size_t)row2 * DK_ + ko);
    const bf16x8 qs1 = *(const bf16x8*)(qB + (size_t)row2 * DK_ + ko + 32);
#pragma unroll
    for (int jj = 0; jj < 8; ++jj) {
      float f0 = bf2f((u16)qa0[jj]), f1 = bf2f((u16)qa1[jj]);
      float g0 = bf2f((u16)qs0[jj]), g1 = bf2f((u16)qs1[jj]);
      float u0 = buH[ko + jj], u1 = buH[ko + 32 + jj];
      float v0 = bvH[ko + jj], v1 = bvH[ko + 32 + jj];
      quf[0][jj] = (short)f2bf(f0 + u0);
      quf[1][jj] = (short)f2bf(f1 + u1);
      qvf[0][jj] = (short)f2bf(f0 + v0);
      qvf[1][jj] = (short)f2bf(f1 + v1);
      qsf[0][jj] = (short)f2bf(g0 + v0);
      qsf[1][jj] = (short)f2bf(g1 + v1);
    }
  }

  f32x4 o[4] = {};
  float mrun[4], lrun[4];
  float sv[4][4];
#pragma unroll
  for (int r = 0; r < 4; ++r) { mrun[r] = -1e30f; lrun[r] = 0.f; }

  const int rbase = 48 - w * 16;
  u16* bandw = &scr[w][0];
  const int lrow = l & 15;
  const int c0s = ((l >> 4) ^ (l & 7)) * 8;  // swizzled chunk offsets (u16 units)
  const int c1s = c0s ^ 32;

  // 17 iterations: kt==qb is split into (lower-band partial, upper-band finalize)
  for (int it = 0; it <= 16; ++it) {
    const int kt = it - (it > qb ? 1 : 0);
    const bool phaseU = (it > qb);
    const bool repeat = (it == qb + 1);
    const bool partial = (it == qb);
    const int k0 = kt * 64;
    const int rr0 = tid >> 3;
    const int cg8 = ((tid & 7) ^ (rr0 & 7)) * 8;  // inverse-swizzled source chunk

    __syncthreads();  // prior reads of k/v/p done
    if (!repeat) {
      const u16* g = kB + (size_t)(k0 + rr0) * DK_ + cg8;
      u16* s = &k_lds[tid * 8];
      async16(g, s);
      async16(g + 32 * DK_, s + 32 * 64);
      const u16* g2 = vB + (size_t)rr0 * T_ + k0 + cg8;
      u16* s2 = &v_lds[tid * 8];
      async16(g2, s2);
      async16(g2 + 32 * T_, s2 + 32 * 64);
    }
    {
      const int jb = phaseU ? (k0 - q0 - 65) : (T_ - 64 + k0 - q0);
#pragma unroll
      for (int i = 0; i < 4; ++i) {
        int rr = i * 32 + rr0;
        int j = jb + rr; j = j < 0 ? 0 : (j > T_ - 1 ? T_ - 1 : j);
        async16(pB + (size_t)j * DK_ + cg8, &p_lds[rr * 64 + (tid & 7) * 8]);
      }
    }
    __syncthreads();  // staging complete

    if (!repeat) {
      // ac = qu . k^T
#pragma unroll
      for (int nf = 0; nf < 4; ++nf) {
        const u16* kb0 = &k_lds[(nf * 16 + lrow) * 64];
        bf16x8 b0 = *(const bf16x8*)(kb0 + c0s);
        bf16x8 b1 = *(const bf16x8*)(kb0 + c1s);
        f32x4 acs = {};
        acs = mfma16(quf[0], b0, acs);
        acs = mfma16(quf[1], b1, acs);
#pragma unroll
        for (int r = 0; r < 4; ++r) sv[nf][r] = acs[r];
      }
    }

    // band term
    {
      bf16x8 A0, A1;
      if (phaseU) { A0 = qsf[0]; A1 = qsf[1]; } else { A0 = qvf[0]; A1 = qvf[1]; }
#pragma unroll
      for (int fu = 0; fu < 5; ++fu) {
        const u16* pb0 = &p_lds[(rbase + fu * 16 + lrow) * 64];
        bf16x8 p0 = *(const bf16x8*)(pb0 + c0s);
        bf16x8 p1 = *(const bf16x8*)(pb0 + c1s);
        f32x4 c = {};
        c = mfma16(A0, p0, c);
        c = mfma16(A1, p1, c);
#pragma unroll
        for (int r = 0; r < 4; ++r)
          bandw[((l >> 4) * 4 + r) * 84 + fu * 16 + lrow] = f2bf(c[r]);
      }
      if (phaseU) {
#pragma unroll
        for (int nf = 0; nf < 4; ++nf)
#pragma unroll
          for (int r = 0; r < 4; ++r) {
            int qrow = (l >> 4) * 4 + r;
            int kcol = nf * 16 + lrow;
            int rel = (k0 + kcol) - (q0 + w * 16 + qrow);
            if (rel >= 2) sv[nf][r] += bf2f(bandw[qrow * 84 + kcol - qrow + 15]);
          }
      } else {
#pragma unroll
        for (int nf = 0; nf < 4; ++nf)
#pragma unroll
          for (int r = 0; r < 4; ++r) {
            int qrow = (l >> 4) * 4 + r;
            int kcol = nf * 16 + lrow;
            int rel = (k0 + kcol) - (q0 + w * 16 + qrow);
            if (rel <= 0) sv[nf][r] += bf2f(bandw[qrow * 84 + kcol - qrow + 15]);
          }
      }
    }

    if (!partial) {
#pragma unroll
      for (int nf = 0; nf < 4; ++nf)
#pragma unroll
        for (int r = 0; r < 4; ++r) sv[nf][r] *= 0.125f;

      // online softmax
      float mnew[4], scl[4];
#pragma unroll
      for (int r = 0; r < 4; ++r) {
        float mx = fmaxf(fmaxf(sv[0][r], sv[1][r]), fmaxf(sv[2][r], sv[3][r]));
#pragma unroll
        for (int off = 1; off < 16; off <<= 1) mx = fmaxf(mx, __shfl_xor(mx, off, 64));
        mnew[r] = fmaxf(mrun[r], mx);
        scl[r] = __expf(mrun[r] - mnew[r]);
        mrun[r] = mnew[r];
      }
#pragma unroll
      for (int r = 0; r < 4; ++r) {
        float s0 = 0.f;
#pragma unroll
        for (int nf = 0; nf < 4; ++nf) {
          float p = __expf(sv[nf][r] - mnew[r]);
          sv[nf][r] = p;
          s0 += p;
        }
#pragma unroll
        for (int off = 1; off < 16; off <<= 1) s0 += __shfl_xor(s0, off, 64);
        lrun[r] = lrun[r] * scl[r] + s0;
      }
#pragma unroll
      for (int df = 0; df < 4; ++df)
#pragma unroll
        for (int r = 0; r < 4; ++r) o[df][r] *= scl[r];

      // P -> LDS (stride 72), re-read as A fragments
#pragma unroll
      for (int nf = 0; nf < 4; ++nf)
#pragma unroll
        for (int r = 0; r < 4; ++r)
          bandw[((l >> 4) * 4 + r) * 72 + nf * 16 + lrow] = f2bf(sv[nf][r]);

      bf16x8 pa0 = *(const bf16x8*)&bandw[lrow * 72 + (l >> 4) * 8];
      bf16x8 pa1 = *(const bf16x8*)&bandw[lrow * 72 + 32 + (l >> 4) * 8];
#pragma unroll
      for (int df = 0; df < 4; ++df) {
        const u16* vb2 = &v_lds[(df * 16 + lrow) * 64];
        bf16x8 v0 = *(const bf16x8*)(vb2 + c0s);
        bf16x8 v1 = *(const bf16x8*)(vb2 + c1s);
        o[df] = mfma16(pa0, v0, o[df]);
        o[df] = mfma16(pa1, v1, o[df]);
      }
    }
  }

#pragma unroll
  for (int df = 0; df < 4; ++df)
#pragma unroll
    for (int r = 0; r < 4; ++r) {
      int qq = q0 + w * 16 + (l >> 4) * 4 + r;
      int dk = df * 16 + (l & 15);
      float val = o[df][r] / lrun[r];
      ao[((size_t)b * T_ + qq) * D_ + h * DK_ + dk] = f2bf(val);
    }
}

extern "C" void kernel_launch(void* const* d_in, const int* in_sizes, int n_in,
                              void* d_out, int out_size, void* d_ws, size_t ws_size,
                              hipStream_t stream) {
  const float* inputs = (const float*)d_in[0];
  const float* ln1_g = (const float*)d_in[1];
  const float* ln1_b = (const float*)d_in[2];
  const float* ln2_g = (const float*)d_in[3];
  const float* ln2_b = (const float*)d_in[4];
  const float* W_qkv = (const float*)d_in[5];
  const float* W_pos = (const float*)d_in[6];
  const float* W_out = (const float*)d_in[7];
  const float* b_out = (const float*)d_in[8];
  const float* pbu = (const float*)d_in[9];
  const float* pbv = (const float*)d_in[10];
  float* out = (float*)d_out;

  char* ws = (char*)d_ws;
  size_t off = 0;
  auto alloc = [&](size_t bytes) {
    char* p = ws + off;
    off += (bytes + 255) & ~(size_t)255;
    return p;
  };
  u16* xn   = (u16*)alloc((size_t)M_ * D_ * 2);
  u16* wqkv = (u16*)alloc((size_t)3 * D_ * D_ * 2);
  u16* wpos = (u16*)alloc((size_t)D_ * D_ * 2);
  u16* wout = (u16*)alloc((size_t)D_ * D_ * 2);
  u16* pemb = (u16*)alloc((size_t)T_ * D_ * 2);
  u16* qB   = (u16*)alloc((size_t)M_ * D_ * 2);
  u16* kbB  = (u16*)alloc((size_t)M_ * D_ * 2);
  u16* vtB  = (u16*)alloc((size_t)M_ * D_ * 2);
  u16* pbuf = (u16*)alloc((size_t)H_ * T_ * DK_ * 2);
  u16* aoB  = (u16*)alloc((size_t)M_ * D_ * 2);
  if (ws_size < off) return;  // insufficient scratch -> visible validation failure

  cast3_k<<<(5 * D_ * D_ / 4 + 255) / 256, 256, 0, stream>>>(W_qkv, W_pos, W_out,
                                                             wqkv, wpos, wout);
  posemb_k<<<T_, 256, 0, stream>>>(inputs, pemb);
  ln2_k<<<M_, 256, 0, stream>>>(inputs, ln1_g, ln1_b, ln2_g, ln2_b, xn);

  gemm_k<1><<<dim3(T_ / 128, D_ / 128), 256, 0, stream>>>(
      pemb, wpos, T_, D_, D_, pbuf, nullptr, nullptr, nullptr, nullptr);
  gemm_k<0><<<dim3(M_ / 128, (3 * D_) / 128), 256, 0, stream>>>(
      xn, wqkv, M_, 3 * D_, D_, qB, kbB, vtB, nullptr, nullptr);
  attn_k<<<1024, 256, 0, stream>>>(qB, kbB, vtB, pbuf, pbu, pbv, aoB);
  gemm_k<2><<<dim3(M_ / 128, D_ / 128), 256, 0, stream>>>(
      aoB, wout, M_, D_, D_, nullptr, nullptr, nullptr, out, b_out);
}

// Round 4
// 137.605 us; speedup vs baseline: 1.5419x; 1.3072x over previous
//
#include <hip/hip_runtime.h>
#include <stdint.h>

#define B_ 8
#define T_ 1024
#define D_ 512
#define H_ 8
#define DK_ 64
#define M_ (B_*T_)

// prep_k block partition
#define PREP_CAST_BLKS (5 * D_ * D_ / 4 / 256)   // 1280
#define PREP_POS_BLKS  (T_)                      // 1024
#define PREP_LN_BLKS   (M_)                      // 8192
#define PREP_BLKS      (PREP_CAST_BLKS + PREP_POS_BLKS + PREP_LN_BLKS)

typedef unsigned short u16;
typedef __attribute__((ext_vector_type(8))) short bf16x8;
typedef __attribute__((ext_vector_type(4))) float f32x4;

static __device__ __forceinline__ u16 f2bf(float f) {
  union { float f; unsigned u; } v; v.f = f;
  unsigned r = (v.u + 0x7fffu + ((v.u >> 16) & 1u)) >> 16;
  return (u16)r;
}
static __device__ __forceinline__ u16 f2bf_ru(float f) {  // round-half-up (positive vals)
  union { float f; unsigned u; } v; v.f = f;
  return (u16)((v.u + 0x8000u) >> 16);
}
static __device__ __forceinline__ float bf2f(u16 u) {
  union { unsigned u; float f; } v; v.u = ((unsigned)u) << 16;
  return v.f;
}
static __device__ __forceinline__ void async16(const u16* g, u16* l) {
  __builtin_amdgcn_global_load_lds(
      (const __attribute__((address_space(1))) void*)g,
      (__attribute__((address_space(3))) void*)l, 16, 0, 0);
}
static __device__ __forceinline__ f32x4 mfma16(bf16x8 a, bf16x8 b, f32x4 c) {
  return __builtin_amdgcn_mfma_f32_16x16x32_bf16(a, b, c, 0, 0, 0);
}

// ---------------- merged prep: weight casts + posemb + double-LN ----------------
__global__ __launch_bounds__(256)
void prep_k(const float* __restrict__ wq, const float* __restrict__ wp,
            const float* __restrict__ wo, u16* __restrict__ dq,
            u16* __restrict__ dp, u16* __restrict__ dwo,
            const float* __restrict__ x, u16* __restrict__ pe,
            const float* __restrict__ g1, const float* __restrict__ b1,
            const float* __restrict__ g2, const float* __restrict__ b2,
            u16* __restrict__ xn) {
  __shared__ float red[16];
  const int blk = blockIdx.x;
  const int t = threadIdx.x;
  if (blk < PREP_CAST_BLKS) {  // weight casts, float4 granularity
    const int na = 3 * D_ * D_ / 4, nb = D_ * D_ / 4;
    int i = blk * 256 + t;
    const float* s; u16* d; int j;
    if (i < na) { s = wq; d = dq; j = i; }
    else if (i < na + nb) { s = wp; d = dp; j = i - na; }
    else { s = wo; d = dwo; j = i - na - nb; }
    float4 v = ((const float4*)s)[j];
    ushort4 o;
    o.x = f2bf(v.x); o.y = f2bf(v.y); o.z = f2bf(v.z); o.w = f2bf(v.w);
    ((ushort4*)d)[j] = o;
  } else if (blk < PREP_CAST_BLKS + PREP_POS_BLKS) {  // positional embedding
    const int tt = blk - PREP_CAST_BLKS;
    float pos = x[(size_t)tt * D_];
    float invf = expf(-(2.f * t / (float)D_) * 9.210340371976184f);
    float ang = pos * invf;
    pe[(size_t)tt * D_ + t] = f2bf(sinf(ang));
    pe[(size_t)tt * D_ + 256 + t] = f2bf(cosf(ang));
  } else {  // fused double layernorm
    const int row = blk - PREP_CAST_BLKS - PREP_POS_BLKS;
    const float2 v = *(const float2*)(x + (size_t)row * D_ + t * 2);
    float a = v.x + v.y;
    float b = v.x * v.x + v.y * v.y;
    for (int off = 32; off; off >>= 1) { a += __shfl_down(a, off, 64); b += __shfl_down(b, off, 64); }
    if ((t & 63) == 0) { red[t >> 6] = a; red[8 + (t >> 6)] = b; }
    __syncthreads();
    a = red[0] + red[1] + red[2] + red[3];
    b = red[8] + red[9] + red[10] + red[11];
    float mu = a * (1.f / D_);
    float var = b * (1.f / D_) - mu * mu;
    float rs = rsqrtf(var + 1e-5f);
    const float2 g1v = *(const float2*)(g1 + t * 2);
    const float2 b1v = *(const float2*)(b1 + t * 2);
    float y0 = (v.x - mu) * rs * g1v.x + b1v.x;
    float y1 = (v.y - mu) * rs * g1v.y + b1v.y;
    __syncthreads();
    a = y0 + y1;
    b = y0 * y0 + y1 * y1;
    for (int off = 32; off; off >>= 1) { a += __shfl_down(a, off, 64); b += __shfl_down(b, off, 64); }
    if ((t & 63) == 0) { red[t >> 6] = a; red[8 + (t >> 6)] = b; }
    __syncthreads();
    a = red[0] + red[1] + red[2] + red[3];
    b = red[8] + red[9] + red[10] + red[11];
    mu = a * (1.f / D_);
    var = b * (1.f / D_) - mu * mu;
    rs = rsqrtf(var + 1e-5f);
    const float2 g2v = *(const float2*)(g2 + t * 2);
    const float2 b2v = *(const float2*)(b2 + t * 2);
    u16* o = xn + (size_t)row * D_ + t * 2;
    o[0] = f2bf((y0 - mu) * rs * g2v.x + b2v.x);
    o[1] = f2bf((y1 - mu) * rs * g2v.y + b2v.y);
  }
}

// ---------------- bf16 GEMM: C = A(MxK) @ W(NxK)^T, templated epilogue ----------------
template<int MODE>
__global__ __launch_bounds__(256, 2)
void gemm_k(const u16* __restrict__ A, const u16* __restrict__ Bw,
            int M, int N, int K,
            u16* __restrict__ o0, u16* __restrict__ o1, u16* __restrict__ o2,
            float* __restrict__ fo, const float* __restrict__ bo) {
  __shared__ u16 As[2][128 * 32];
  __shared__ u16 Bs[2][128 * 32];
  const int tid = threadIdx.x;
  const int l = tid & 63, w = tid >> 6;
  const int m0 = blockIdx.x * 128, n0 = blockIdx.y * 128;
  const int wm = (w >> 1) * 64, wn = (w & 1) * 64;
  const int nk = K >> 5;

  auto stage = [&](int bufi, int kt) {
    const int row = tid >> 2;
    const int cg = ((tid & 3) ^ ((row + (row >> 2)) & 3)) * 8;
    const u16* ga = A + (size_t)(m0 + row) * K + kt * 32 + cg;
    u16* la = &As[bufi][tid * 8];
    async16(ga, la);
    async16(ga + (size_t)64 * K, la + 64 * 32);
    const u16* gb = Bw + (size_t)(n0 + row) * K + kt * 32 + cg;
    u16* lb = &Bs[bufi][tid * 8];
    async16(gb, lb);
    async16(gb + (size_t)64 * K, lb + 64 * 32);
  };

  const int fl = (((l & 15) + ((l & 15) >> 2)) & 3);
  const int coff = ((l >> 4) ^ fl) * 8;
  const int aoff = (l & 15) * 32 + coff;

  f32x4 acc[4][4] = {};
  stage(0, 0);
  for (int kt = 0; kt < nk; ++kt) {
    __syncthreads();
    if (kt + 1 < nk) stage((kt + 1) & 1, kt + 1);
    const u16* as = As[kt & 1];
    const u16* bs = Bs[kt & 1];
    bf16x8 af[4], bfr[4];
#pragma unroll
    for (int i = 0; i < 4; ++i)
      af[i] = *(const bf16x8*)&as[(wm + i * 16) * 32 + aoff];
#pragma unroll
    for (int j = 0; j < 4; ++j)
      bfr[j] = *(const bf16x8*)&bs[(wn + j * 16) * 32 + aoff];
#pragma unroll
    for (int i = 0; i < 4; ++i)
#pragma unroll
      for (int j = 0; j < 4; ++j)
        acc[i][j] = mfma16(af[i], bfr[j], acc[i][j]);
  }

#pragma unroll
  for (int i = 0; i < 4; ++i)
#pragma unroll
    for (int j = 0; j < 4; ++j) {
      const int row0 = m0 + wm + i * 16 + ((l >> 4) << 2);
      const int col = n0 + wn + j * 16 + (l & 15);
      if (MODE == 0) {
        const int sec = col >> 9, cc = col & 511;
        const int hh = cc >> 6, dk = cc & 63;
        const int bb = row0 >> 10, t0r = row0 & 1023;
        if (sec == 2) {
          ushort4 v4;
          v4.x = f2bf(acc[i][j][0]); v4.y = f2bf(acc[i][j][1]);
          v4.z = f2bf(acc[i][j][2]); v4.w = f2bf(acc[i][j][3]);
          *(ushort4*)&o2[((size_t)(bb * H_ + hh) * DK_ + dk) * T_ + t0r] = v4;
        } else {
          u16* dst = (sec == 0) ? o0 : o1;
#pragma unroll
          for (int r = 0; r < 4; ++r)
            dst[((size_t)(bb * H_ + hh) * T_ + t0r + r) * DK_ + dk] = f2bf(acc[i][j][r]);
        }
      } else if (MODE == 1) {
        const int hh = col >> 6, dk = col & 63;
#pragma unroll
        for (int r = 0; r < 4; ++r)
          o0[((size_t)hh * T_ + row0 + r) * DK_ + dk] = f2bf(acc[i][j][r]);
      } else {
#pragma unroll
        for (int r = 0; r < 4; ++r)
          fo[(size_t)(row0 + r) * D_ + col] = acc[i][j][r] + bo[col];
      }
    }
}

// ---------------- fused rel-attention ----------------
// No online max (scores |s| <~ 4, exact softmax shift-invariance); deferred
// denominator; scale 0.125*log2e folded into q frags; fp32 band scratch.
__global__ __launch_bounds__(256, 3)
void attn_k(const u16* __restrict__ q, const u16* __restrict__ kb,
            const u16* __restrict__ vt, const u16* __restrict__ pb,
            const float* __restrict__ bu, const float* __restrict__ bv,
            u16* __restrict__ ao) {
  __shared__ u16 k_lds[64 * 64];
  __shared__ u16 v_lds[64 * 64];
  __shared__ u16 p_lds[128 * 64];
  __shared__ float scr[4][16 * 83];  // per-wave: fp32 band (stride 83) / bf16 P (stride 72)

  const int tid = threadIdx.x;
  const int l = tid & 63, w = tid >> 6;
  const int dd = blockIdx.x;
  const int bh = (dd & 7) * 8 + (dd >> 7);
  const int qb = (dd >> 3) & 15;
  const int q0 = qb * 64;
  const int b = bh >> 3, h = bh & 7;

  const u16* qB = q + (size_t)bh * T_ * DK_;
  const u16* kB = kb + (size_t)bh * T_ * DK_;
  const u16* vB = vt + (size_t)bh * DK_ * T_;
  const u16* pB = pb + (size_t)h * T_ * DK_;

  const float SCALE = 0.125f * 1.4426950408889634f;  // fold 1/sqrt(DK) and log2(e)

  bf16x8 quf[2], qvf[2], qsf[2];
  {
    const float* buH = bu + h * DK_;
    const float* bvH = bv + h * DK_;
    const int row = q0 + w * 16 + (l & 15);
    const int row2 = (row + 1 < T_) ? row + 1 : T_ - 1;
    const int ko = (l >> 4) * 8;
    const bf16x8 qa0 = *(const bf16x8*)(qB + (size_t)row * DK_ + ko);
    const bf16x8 qa1 = *(const bf16x8*)(qB + (size_t)row * DK_ + ko + 32);
    const bf16x8 qs0 = *(const bf16x8*)(qB + (size_t)row2 * DK_ + ko);
    const bf16x8 qs1 = *(const bf16x8*)(qB + (size_t)row2 * DK_ + ko + 32);
#pragma unroll
    for (int jj = 0; jj < 8; ++jj) {
      float f0 = bf2f((u16)qa0[jj]), f1 = bf2f((u16)qa1[jj]);
      float g0 = bf2f((u16)qs0[jj]), g1 = bf2f((u16)qs1[jj]);
      float u0 = buH[ko + jj], u1 = buH[ko + 32 + jj];
      float v0 = bvH[ko + jj], v1 = bvH[ko + 32 + jj];
      quf[0][jj] = (short)f2bf((f0 + u0) * SCALE);
      quf[1][jj] = (short)f2bf((f1 + u1) * SCALE);
      qvf[0][jj] = (short)f2bf((f0 + v0) * SCALE);
      qvf[1][jj] = (short)f2bf((f1 + v1) * SCALE);
      qsf[0][jj] = (short)f2bf((g0 + v0) * SCALE);
      qsf[1][jj] = (short)f2bf((g1 + v1) * SCALE);
    }
  }

  f32x4 o[4] = {};
  float lrun[4] = {0.f, 0.f, 0.f, 0.f};
  float sv[4][4];

  const int rbase = 48 - w * 16;
  float* bandf = &scr[w][0];
  u16* pwv = (u16*)&scr[w][0];
  const int lrow = l & 15;
  const int c0s = ((l >> 4) ^ (l & 7)) * 8;
  const int c1s = c0s ^ 32;
  const int qrow0 = (l >> 4) * 4;

  for (int it = 0; it <= 16; ++it) {
    const int kt = it - (it > qb ? 1 : 0);
    const bool phaseU = (it > qb);
    const bool repeat = (it == qb + 1);
    const bool partial = (it == qb);
    const bool needMask = (it >= qb) && (it <= qb + 2);
    const int k0 = kt * 64;
    const int rr0 = tid >> 3;
    const int cg8 = ((tid & 7) ^ (rr0 & 7)) * 8;

    __syncthreads();
    if (!repeat) {
      const u16* g = kB + (size_t)(k0 + rr0) * DK_ + cg8;
      u16* s = &k_lds[tid * 8];
      async16(g, s);
      async16(g + 32 * DK_, s + 32 * 64);
      const u16* g2 = vB + (size_t)rr0 * T_ + k0 + cg8;
      u16* s2 = &v_lds[tid * 8];
      async16(g2, s2);
      async16(g2 + 32 * T_, s2 + 32 * 64);
    }
    {
      const int jb = phaseU ? (k0 - q0 - 65) : (T_ - 64 + k0 - q0);
#pragma unroll
      for (int i = 0; i < 4; ++i) {
        int rr = i * 32 + rr0;
        int j = jb + rr; j = j < 0 ? 0 : (j > T_ - 1 ? T_ - 1 : j);
        async16(pB + (size_t)j * DK_ + cg8, &p_lds[rr * 64 + (tid & 7) * 8]);
      }
    }
    __syncthreads();

    if (!repeat) {  // ac = qu . k^T
      __builtin_amdgcn_s_setprio(1);
#pragma unroll
      for (int nf = 0; nf < 4; ++nf) {
        const u16* kb0 = &k_lds[(nf * 16 + lrow) * 64];
        bf16x8 b0 = *(const bf16x8*)(kb0 + c0s);
        bf16x8 b1 = *(const bf16x8*)(kb0 + c1s);
        f32x4 acs = {};
        acs = mfma16(quf[0], b0, acs);
        acs = mfma16(quf[1], b1, acs);
#pragma unroll
        for (int r = 0; r < 4; ++r) sv[nf][r] = acs[r];
      }
      __builtin_amdgcn_s_setprio(0);
    }

    {  // band term -> fp32 scratch
      bf16x8 A0, A1;
      if (phaseU) { A0 = qsf[0]; A1 = qsf[1]; } else { A0 = qvf[0]; A1 = qvf[1]; }
      __builtin_amdgcn_s_setprio(1);
#pragma unroll
      for (int fu = 0; fu < 5; ++fu) {
        const u16* pb0 = &p_lds[(rbase + fu * 16 + lrow) * 64];
        bf16x8 p0 = *(const bf16x8*)(pb0 + c0s);
        bf16x8 p1 = *(const bf16x8*)(pb0 + c1s);
        f32x4 c = {};
        c = mfma16(A0, p0, c);
        c = mfma16(A1, p1, c);
#pragma unroll
        for (int r = 0; r < 4; ++r)
          bandf[(qrow0 + r) * 83 + fu * 16 + lrow] = c[r];
      }
      __builtin_amdgcn_s_setprio(0);
      if (needMask) {
        if (phaseU) {
#pragma unroll
          for (int nf = 0; nf < 4; ++nf)
#pragma unroll
            for (int r = 0; r < 4; ++r) {
              int qrow = qrow0 + r;
              int kcol = nf * 16 + lrow;
              int rel = (k0 + kcol) - (q0 + w * 16 + qrow);
              if (rel >= 2) sv[nf][r] += bandf[qrow * 83 + kcol - qrow + 15];
            }
        } else {
#pragma unroll
          for (int nf = 0; nf < 4; ++nf)
#pragma unroll
            for (int r = 0; r < 4; ++r) {
              int qrow = qrow0 + r;
              int kcol = nf * 16 + lrow;
              int rel = (k0 + kcol) - (q0 + w * 16 + qrow);
              if (rel <= 0) sv[nf][r] += bandf[qrow * 83 + kcol - qrow + 15];
            }
        }
      } else {
#pragma unroll
        for (int nf = 0; nf < 4; ++nf)
#pragma unroll
          for (int r = 0; r < 4; ++r) {
            int qrow = qrow0 + r;
            int kcol = nf * 16 + lrow;
            sv[nf][r] += bandf[qrow * 83 + kcol - qrow + 15];
          }
      }
    }

    if (!partial) {
      // p = exp2(sv); deferred denominator
#pragma unroll
      for (int nf = 0; nf < 4; ++nf)
#pragma unroll
        for (int r = 0; r < 4; ++r)
          sv[nf][r] = __builtin_amdgcn_exp2f(sv[nf][r]);
#pragma unroll
      for (int r = 0; r < 4; ++r)
        lrun[r] += (sv[0][r] + sv[1][r]) + (sv[2][r] + sv[3][r]);

      __builtin_amdgcn_sched_barrier(0);  // band reads before P overwrite (aliased scr)
#pragma unroll
      for (int nf = 0; nf < 4; ++nf)
#pragma unroll
        for (int r = 0; r < 4; ++r)
          pwv[(qrow0 + r) * 72 + nf * 16 + lrow] = f2bf_ru(sv[nf][r]);

      bf16x8 pa0 = *(const bf16x8*)&pwv[lrow * 72 + (l >> 4) * 8];
      bf16x8 pa1 = *(const bf16x8*)&pwv[lrow * 72 + 32 + (l >> 4) * 8];
      __builtin_amdgcn_s_setprio(1);
#pragma unroll
      for (int df = 0; df < 4; ++df) {
        const u16* vb2 = &v_lds[(df * 16 + lrow) * 64];
        bf16x8 v0 = *(const bf16x8*)(vb2 + c0s);
        bf16x8 v1 = *(const bf16x8*)(vb2 + c1s);
        o[df] = mfma16(pa0, v0, o[df]);
        o[df] = mfma16(pa1, v1, o[df]);
      }
      __builtin_amdgcn_s_setprio(0);
    }
  }

  // final denominator reduce over the 16-lane col groups
#pragma unroll
  for (int r = 0; r < 4; ++r) {
#pragma unroll
    for (int off = 1; off < 16; off <<= 1) lrun[r] += __shfl_xor(lrun[r], off, 64);
    lrun[r] = 1.f / lrun[r];
  }
#pragma unroll
  for (int df = 0; df < 4; ++df)
#pragma unroll
    for (int r = 0; r < 4; ++r) {
      int qq = q0 + w * 16 + (l >> 4) * 4 + r;
      int dk = df * 16 + (l & 15);
      float val = o[df][r] * lrun[r];
      ao[((size_t)b * T_ + qq) * D_ + h * DK_ + dk] = f2bf(val);
    }
}

extern "C" void kernel_launch(void* const* d_in, const int* in_sizes, int n_in,
                              void* d_out, int out_size, void* d_ws, size_t ws_size,
                              hipStream_t stream) {
  const float* inputs = (const float*)d_in[0];
  const float* ln1_g = (const float*)d_in[1];
  const float* ln1_b = (const float*)d_in[2];
  const float* ln2_g = (const float*)d_in[3];
  const float* ln2_b = (const float*)d_in[4];
  const float* W_qkv = (const float*)d_in[5];
  const float* W_pos = (const float*)d_in[6];
  const float* W_out = (const float*)d_in[7];
  const float* b_out = (const float*)d_in[8];
  const float* pbu = (const float*)d_in[9];
  const float* pbv = (const float*)d_in[10];
  float* out = (float*)d_out;

  char* ws = (char*)d_ws;
  size_t off = 0;
  auto alloc = [&](size_t bytes) {
    char* p = ws + off;
    off += (bytes + 255) & ~(size_t)255;
    return p;
  };
  u16* xn   = (u16*)alloc((size_t)M_ * D_ * 2);
  u16* wqkv = (u16*)alloc((size_t)3 * D_ * D_ * 2);
  u16* wpos = (u16*)alloc((size_t)D_ * D_ * 2);
  u16* wout = (u16*)alloc((size_t)D_ * D_ * 2);
  u16* pemb = (u16*)alloc((size_t)T_ * D_ * 2);
  u16* qB   = (u16*)alloc((size_t)M_ * D_ * 2);
  u16* kbB  = (u16*)alloc((size_t)M_ * D_ * 2);
  u16* vtB  = (u16*)alloc((size_t)M_ * D_ * 2);
  u16* pbuf = (u16*)alloc((size_t)H_ * T_ * DK_ * 2);
  u16* aoB  = (u16*)alloc((size_t)M_ * D_ * 2);
  if (ws_size < off) return;

  prep_k<<<PREP_BLKS, 256, 0, stream>>>(W_qkv, W_pos, W_out, wqkv, wpos, wout,
                                        inputs, pemb, ln1_g, ln1_b, ln2_g, ln2_b, xn);
  gemm_k<1><<<dim3(T_ / 128, D_ / 128), 256, 0, stream>>>(
      pemb, wpos, T_, D_, D_, pbuf, nullptr, nullptr, nullptr, nullptr);
  gemm_k<0><<<dim3(M_ / 128, (3 * D_) / 128), 256, 0, stream>>>(
      xn, wqkv, M_, 3 * D_, D_, qB, kbB, vtB, nullptr, nullptr);
  attn_k<<<1024, 256, 0, stream>>>(qB, kbB, vtB, pbuf, pbu, pbv, aoB);
  gemm_k<2><<<dim3(M_ / 128, D_ / 128), 256, 0, stream>>>(
      aoB, wout, M_, D_, D_, nullptr, nullptr, nullptr, out, b_out);
}

// Round 5
// 137.442 us; speedup vs baseline: 1.5437x; 1.0012x over previous
//
#include <hip/hip_runtime.h>
#include <stdint.h>

#define B_ 8
#define T_ 1024
#define D_ 512
#define H_ 8
#define DK_ 64
#define M_ (B_*T_)

// prep_k block partition
#define PREP_CAST_BLKS (5 * D_ * D_ / 4 / 256)   // 1280
#define PREP_POS_BLKS  (T_)                      // 1024
#define PREP_LN_BLKS   (M_)                      // 8192
#define PREP_BLKS      (PREP_CAST_BLKS + PREP_POS_BLKS + PREP_LN_BLKS)

typedef unsigned short u16;
typedef __attribute__((ext_vector_type(8))) short bf16x8;
typedef __attribute__((ext_vector_type(4))) float f32x4;

static __device__ __forceinline__ u16 f2bf(float f) {
  union { float f; unsigned u; } v; v.f = f;
  unsigned r = (v.u + 0x7fffu + ((v.u >> 16) & 1u)) >> 16;
  return (u16)r;
}
static __device__ __forceinline__ u16 f2bf_ru(float f) {  // round-half-up (positive vals)
  union { float f; unsigned u; } v; v.f = f;
  return (u16)((v.u + 0x8000u) >> 16);
}
static __device__ __forceinline__ float bf2f(u16 u) {
  union { unsigned u; float f; } v; v.u = ((unsigned)u) << 16;
  return v.f;
}
static __device__ __forceinline__ void async16(const u16* g, u16* l) {
  __builtin_amdgcn_global_load_lds(
      (const __attribute__((address_space(1))) void*)g,
      (__attribute__((address_space(3))) void*)l, 16, 0, 0);
}
static __device__ __forceinline__ f32x4 mfma16(bf16x8 a, bf16x8 b, f32x4 c) {
  return __builtin_amdgcn_mfma_f32_16x16x32_bf16(a, b, c, 0, 0, 0);
}

// ---------------- merged prep: weight casts + posemb + double-LN ----------------
__global__ __launch_bounds__(256)
void prep_k(const float* __restrict__ wq, const float* __restrict__ wp,
            const float* __restrict__ wo, u16* __restrict__ dq,
            u16* __restrict__ dp, u16* __restrict__ dwo,
            const float* __restrict__ x, u16* __restrict__ pe,
            const float* __restrict__ g1, const float* __restrict__ b1,
            const float* __restrict__ g2, const float* __restrict__ b2,
            u16* __restrict__ xn) {
  __shared__ float red[16];
  const int blk = blockIdx.x;
  const int t = threadIdx.x;
  if (blk < PREP_CAST_BLKS) {  // weight casts, float4 granularity
    const int na = 3 * D_ * D_ / 4, nb = D_ * D_ / 4;
    int i = blk * 256 + t;
    const float* s; u16* d; int j;
    if (i < na) { s = wq; d = dq; j = i; }
    else if (i < na + nb) { s = wp; d = dp; j = i - na; }
    else { s = wo; d = dwo; j = i - na - nb; }
    float4 v = ((const float4*)s)[j];
    ushort4 o;
    o.x = f2bf(v.x); o.y = f2bf(v.y); o.z = f2bf(v.z); o.w = f2bf(v.w);
    ((ushort4*)d)[j] = o;
  } else if (blk < PREP_CAST_BLKS + PREP_POS_BLKS) {  // positional embedding
    const int tt = blk - PREP_CAST_BLKS;
    float pos = x[(size_t)tt * D_];
    float invf = expf(-(2.f * t / (float)D_) * 9.210340371976184f);
    float ang = pos * invf;
    pe[(size_t)tt * D_ + t] = f2bf(sinf(ang));
    pe[(size_t)tt * D_ + 256 + t] = f2bf(cosf(ang));
  } else {  // fused double layernorm
    const int row = blk - PREP_CAST_BLKS - PREP_POS_BLKS;
    const float2 v = *(const float2*)(x + (size_t)row * D_ + t * 2);
    float a = v.x + v.y;
    float b = v.x * v.x + v.y * v.y;
    for (int off = 32; off; off >>= 1) { a += __shfl_down(a, off, 64); b += __shfl_down(b, off, 64); }
    if ((t & 63) == 0) { red[t >> 6] = a; red[8 + (t >> 6)] = b; }
    __syncthreads();
    a = red[0] + red[1] + red[2] + red[3];
    b = red[8] + red[9] + red[10] + red[11];
    float mu = a * (1.f / D_);
    float var = b * (1.f / D_) - mu * mu;
    float rs = rsqrtf(var + 1e-5f);
    const float2 g1v = *(const float2*)(g1 + t * 2);
    const float2 b1v = *(const float2*)(b1 + t * 2);
    float y0 = (v.x - mu) * rs * g1v.x + b1v.x;
    float y1 = (v.y - mu) * rs * g1v.y + b1v.y;
    __syncthreads();
    a = y0 + y1;
    b = y0 * y0 + y1 * y1;
    for (int off = 32; off; off >>= 1) { a += __shfl_down(a, off, 64); b += __shfl_down(b, off, 64); }
    if ((t & 63) == 0) { red[t >> 6] = a; red[8 + (t >> 6)] = b; }
    __syncthreads();
    a = red[0] + red[1] + red[2] + red[3];
    b = red[8] + red[9] + red[10] + red[11];
    mu = a * (1.f / D_);
    var = b * (1.f / D_) - mu * mu;
    rs = rsqrtf(var + 1e-5f);
    const float2 g2v = *(const float2*)(g2 + t * 2);
    const float2 b2v = *(const float2*)(b2 + t * 2);
    u16* o = xn + (size_t)row * D_ + t * 2;
    o[0] = f2bf((y0 - mu) * rs * g2v.x + b2v.x);
    o[1] = f2bf((y1 - mu) * rs * g2v.y + b2v.y);
  }
}

// ---------------- bf16 GEMM: C = A(MxK) @ W(NxK)^T, templated epilogue ----------------
template<int MODE>
__global__ __launch_bounds__(256, 2)
void gemm_k(const u16* __restrict__ A, const u16* __restrict__ Bw,
            int M, int N, int K,
            u16* __restrict__ o0, u16* __restrict__ o1, u16* __restrict__ o2,
            float* __restrict__ fo, const float* __restrict__ bo) {
  __shared__ u16 As[2][128 * 32];
  __shared__ u16 Bs[2][128 * 32];
  const int tid = threadIdx.x;
  const int l = tid & 63, w = tid >> 6;
  const int m0 = blockIdx.x * 128, n0 = blockIdx.y * 128;
  const int wm = (w >> 1) * 64, wn = (w & 1) * 64;
  const int nk = K >> 5;

  auto stage = [&](int bufi, int kt) {
    const int row = tid >> 2;
    const int cg = ((tid & 3) ^ ((row + (row >> 2)) & 3)) * 8;
    const u16* ga = A + (size_t)(m0 + row) * K + kt * 32 + cg;
    u16* la = &As[bufi][tid * 8];
    async16(ga, la);
    async16(ga + (size_t)64 * K, la + 64 * 32);
    const u16* gb = Bw + (size_t)(n0 + row) * K + kt * 32 + cg;
    u16* lb = &Bs[bufi][tid * 8];
    async16(gb, lb);
    async16(gb + (size_t)64 * K, lb + 64 * 32);
  };

  const int fl = (((l & 15) + ((l & 15) >> 2)) & 3);
  const int coff = ((l >> 4) ^ fl) * 8;
  const int aoff = (l & 15) * 32 + coff;

  f32x4 acc[4][4] = {};
  stage(0, 0);
  for (int kt = 0; kt < nk; ++kt) {
    __syncthreads();
    if (kt + 1 < nk) stage((kt + 1) & 1, kt + 1);
    const u16* as = As[kt & 1];
    const u16* bs = Bs[kt & 1];
    bf16x8 af[4], bfr[4];
#pragma unroll
    for (int i = 0; i < 4; ++i)
      af[i] = *(const bf16x8*)&as[(wm + i * 16) * 32 + aoff];
#pragma unroll
    for (int j = 0; j < 4; ++j)
      bfr[j] = *(const bf16x8*)&bs[(wn + j * 16) * 32 + aoff];
#pragma unroll
    for (int i = 0; i < 4; ++i)
#pragma unroll
      for (int j = 0; j < 4; ++j)
        acc[i][j] = mfma16(af[i], bfr[j], acc[i][j]);
  }

#pragma unroll
  for (int i = 0; i < 4; ++i)
#pragma unroll
    for (int j = 0; j < 4; ++j) {
      const int row0 = m0 + wm + i * 16 + ((l >> 4) << 2);
      const int col = n0 + wn + j * 16 + (l & 15);
      if (MODE == 0) {
        const int sec = col >> 9, cc = col & 511;
        const int hh = cc >> 6, dk = cc & 63;
        const int bb = row0 >> 10, t0r = row0 & 1023;
        if (sec == 2) {
          ushort4 v4;
          v4.x = f2bf(acc[i][j][0]); v4.y = f2bf(acc[i][j][1]);
          v4.z = f2bf(acc[i][j][2]); v4.w = f2bf(acc[i][j][3]);
          *(ushort4*)&o2[((size_t)(bb * H_ + hh) * DK_ + dk) * T_ + t0r] = v4;
        } else {
          u16* dst = (sec == 0) ? o0 : o1;
#pragma unroll
          for (int r = 0; r < 4; ++r)
            dst[((size_t)(bb * H_ + hh) * T_ + t0r + r) * DK_ + dk] = f2bf(acc[i][j][r]);
        }
      } else if (MODE == 1) {
        const int hh = col >> 6, dk = col & 63;
#pragma unroll
        for (int r = 0; r < 4; ++r)
          o0[((size_t)hh * T_ + row0 + r) * DK_ + dk] = f2bf(acc[i][j][r]);
      } else {
#pragma unroll
        for (int r = 0; r < 4; ++r)
          fo[(size_t)(row0 + r) * D_ + col] = acc[i][j][r] + bo[col];
      }
    }
}

// ---------------- fused rel-attention v2 ----------------
// T14 reg-staged prefetch (global->reg during compute, reg->LDS at iter top,
// raw s_barrier with lgkmcnt-only wait); bpermute rel-shift gather (no band
// scratch); no-max exp2 softmax with deferred denominator.
__global__ __launch_bounds__(256, 3)
void attn_k(const u16* __restrict__ q, const u16* __restrict__ kb,
            const u16* __restrict__ vt, const u16* __restrict__ pb,
            const float* __restrict__ bu, const float* __restrict__ bv,
            u16* __restrict__ ao) {
  __shared__ u16 k_lds[64 * 64];
  __shared__ u16 v_lds[64 * 64];
  __shared__ u16 p_lds[128 * 64];
  __shared__ u16 pscr[4][16 * 72];  // per-wave P transpose scratch

  const int tid = threadIdx.x;
  const int l = tid & 63, w = tid >> 6;
  const int dd = blockIdx.x;
  const int bh = (dd & 7) * 8 + (dd >> 7);   // XCD-locality remap
  const int qb = (dd >> 3) & 15;
  const int q0 = qb * 64;
  const int b = bh >> 3, h = bh & 7;

  const u16* qB = q + (size_t)bh * T_ * DK_;
  const u16* kB = kb + (size_t)bh * T_ * DK_;
  const u16* vB = vt + (size_t)bh * DK_ * T_;
  const u16* pB = pb + (size_t)h * T_ * DK_;

  const float SCALE = 0.125f * 1.4426950408889634f;  // 1/sqrt(DK) * log2(e)

  bf16x8 quf[2], qvf[2], qsf[2];
  {
    const float* buH = bu + h * DK_;
    const float* bvH = bv + h * DK_;
    const int row = q0 + w * 16 + (l & 15);
    const int row2 = (row + 1 < T_) ? row + 1 : T_ - 1;
    const int ko = (l >> 4) * 8;
    const bf16x8 qa0 = *(const bf16x8*)(qB + (size_t)row * DK_ + ko);
    const bf16x8 qa1 = *(const bf16x8*)(qB + (size_t)row * DK_ + ko + 32);
    const bf16x8 qs0 = *(const bf16x8*)(qB + (size_t)row2 * DK_ + ko);
    const bf16x8 qs1 = *(const bf16x8*)(qB + (size_t)row2 * DK_ + ko + 32);
#pragma unroll
    for (int jj = 0; jj < 8; ++jj) {
      float f0 = bf2f((u16)qa0[jj]), f1 = bf2f((u16)qa1[jj]);
      float g0 = bf2f((u16)qs0[jj]), g1 = bf2f((u16)qs1[jj]);
      float u0 = buH[ko + jj], u1 = buH[ko + 32 + jj];
      float v0 = bvH[ko + jj], v1 = bvH[ko + 32 + jj];
      quf[0][jj] = (short)f2bf((f0 + u0) * SCALE);
      quf[1][jj] = (short)f2bf((f1 + u1) * SCALE);
      qvf[0][jj] = (short)f2bf((f0 + v0) * SCALE);
      qvf[1][jj] = (short)f2bf((f1 + v1) * SCALE);
      qsf[0][jj] = (short)f2bf((g0 + v0) * SCALE);
      qsf[1][jj] = (short)f2bf((g1 + v1) * SCALE);
    }
  }

  f32x4 o[4] = {};
  float lrun[4] = {0.f, 0.f, 0.f, 0.f};
  float sv[4][4];

  const int rbase = 48 - w * 16;
  u16* pwv = &pscr[w][0];
  const int lrow = l & 15;
  const int c0s = ((l >> 4) ^ (l & 7)) * 8;   // swizzled read chunk offsets
  const int c1s = c0s ^ 32;
  const int qrow0 = (l >> 4) * 4;

  // loop-invariant bpermute gather indices: u = kcol - qrow + 15
  int srcb[4], hi[4];
#pragma unroll
  for (int r = 0; r < 4; ++r) {
    int d = lrow - qrow0 - r + 15;            // 0..30
    srcb[r] = (((l >> 4) * 16 + (d & 15)) << 2);
    hi[r] = d >> 4;
  }

  // staging (lane-addressed): linear global source, swizzled LDS dest
  const int rr0 = tid >> 3;                    // 0..31
  const int cb = (tid & 7) * 8;                // u16 col within 64
  const int swz = ((tid & 7) ^ (rr0 & 7)) * 8; // dest chunk (rows+32 same swz)
  const int wkv = rr0 * 64 + swz;

  uint4 kreg0, kreg1, vreg0, vreg1, preg0, preg1, preg2, preg3;
  auto loadKV = [&](int k0n) {
    kreg0 = *(const uint4*)(kB + (size_t)(k0n + rr0) * DK_ + cb);
    kreg1 = *(const uint4*)(kB + (size_t)(k0n + rr0 + 32) * DK_ + cb);
    vreg0 = *(const uint4*)(vB + (size_t)rr0 * T_ + k0n + cb);
    vreg1 = *(const uint4*)(vB + (size_t)(rr0 + 32) * T_ + k0n + cb);
  };
  auto pclamp = [&](int j) { return j < 0 ? 0 : (j > T_ - 1 ? T_ - 1 : j); };
  auto loadP = [&](int jb) {
    preg0 = *(const uint4*)(pB + (size_t)pclamp(jb + rr0) * DK_ + cb);
    preg1 = *(const uint4*)(pB + (size_t)pclamp(jb + 32 + rr0) * DK_ + cb);
    preg2 = *(const uint4*)(pB + (size_t)pclamp(jb + 64 + rr0) * DK_ + cb);
    preg3 = *(const uint4*)(pB + (size_t)pclamp(jb + 96 + rr0) * DK_ + cb);
  };

  // prologue: stage tile for it=0 (lower window, kt=0)
  loadKV(0);
  loadP(T_ - 64 - q0);

  for (int it = 0; it <= 16; ++it) {
    const int kt = it - (it > qb ? 1 : 0);
    const bool phaseU = (it > qb);
    const bool repeat = (it == qb + 1);
    const bool partial = (it == qb);
    const bool needMask = (it >= qb) && (it <= qb + 2);
    const int k0 = kt * 64;

    __syncthreads();  // all waves done reading LDS (prefetched loads landed long ago)
    if (!repeat) {
      *(uint4*)&k_lds[wkv] = kreg0;
      *(uint4*)&k_lds[wkv + 32 * 64] = kreg1;
      *(uint4*)&v_lds[wkv] = vreg0;
      *(uint4*)&v_lds[wkv + 32 * 64] = vreg1;
    }
    *(uint4*)&p_lds[wkv] = preg0;
    *(uint4*)&p_lds[wkv + 32 * 64] = preg1;
    *(uint4*)&p_lds[wkv + 64 * 64] = preg2;
    *(uint4*)&p_lds[wkv + 96 * 64] = preg3;
    asm volatile("s_waitcnt lgkmcnt(0)" ::: "memory");
    __builtin_amdgcn_sched_barrier(0);
    __builtin_amdgcn_s_barrier();   // raw: no vmcnt drain
    __builtin_amdgcn_sched_barrier(0);

    // prefetch next tile into regs (lands during this iter's compute)
    if (it < 16) {
      if (it != qb) loadKV((it + 1 - (it + 1 > qb ? 1 : 0)) * 64);
      const bool pU = (it + 1 > qb);
      const int ktn = it + 1 - (pU ? 1 : 0);
      loadP(pU ? ktn * 64 - q0 - 65 : T_ - 64 + ktn * 64 - q0);
    }

    if (!repeat) {  // ac = qu . k^T
      __builtin_amdgcn_s_setprio(1);
#pragma unroll
      for (int nf = 0; nf < 4; ++nf) {
        const u16* kb0 = &k_lds[(nf * 16 + lrow) * 64];
        bf16x8 b0 = *(const bf16x8*)(kb0 + c0s);
        bf16x8 b1 = *(const bf16x8*)(kb0 + c1s);
        f32x4 acs = {};
        acs = mfma16(quf[0], b0, acs);
        acs = mfma16(quf[1], b1, acs);
#pragma unroll
        for (int r = 0; r < 4; ++r) sv[nf][r] = acs[r];
      }
      __builtin_amdgcn_s_setprio(0);
    }

    {  // band term (registers) + bpermute rel-shift gather
      bf16x8 A0, A1;
      if (phaseU) { A0 = qsf[0]; A1 = qsf[1]; } else { A0 = qvf[0]; A1 = qvf[1]; }
      f32x4 c[5];
      __builtin_amdgcn_s_setprio(1);
#pragma unroll
      for (int fu = 0; fu < 5; ++fu) {
        const u16* pb0 = &p_lds[(rbase + fu * 16 + lrow) * 64];
        bf16x8 p0 = *(const bf16x8*)(pb0 + c0s);
        bf16x8 p1 = *(const bf16x8*)(pb0 + c1s);
        f32x4 cc = {};
        cc = mfma16(A0, p0, cc);
        cc = mfma16(A1, p1, cc);
        c[fu] = cc;
      }
      __builtin_amdgcn_s_setprio(0);
#pragma unroll
      for (int r = 0; r < 4; ++r) {
        float rot[6];
#pragma unroll
        for (int fu = 0; fu < 5; ++fu)
          rot[fu] = __int_as_float(
              __builtin_amdgcn_ds_bpermute(srcb[r], __float_as_int(c[fu][r])));
        rot[5] = 0.f;  // unused
#pragma unroll
        for (int nf = 0; nf < 4; ++nf) {
          float bd = hi[r] ? rot[nf + 1] : rot[nf];
          if (needMask) {
            int rel = (k0 + nf * 16 + lrow) - (q0 + w * 16 + qrow0 + r);
            bool ok = phaseU ? (rel >= 2) : (rel <= 0);
            bd = ok ? bd : 0.f;
          }
          sv[nf][r] += bd;
        }
      }
    }

    if (!partial) {
      // p = exp2(sv); deferred denominator
#pragma unroll
      for (int nf = 0; nf < 4; ++nf)
#pragma unroll
        for (int r = 0; r < 4; ++r)
          sv[nf][r] = __builtin_amdgcn_exp2f(sv[nf][r]);
#pragma unroll
      for (int r = 0; r < 4; ++r)
        lrun[r] += (sv[0][r] + sv[1][r]) + (sv[2][r] + sv[3][r]);

      // P -> per-wave LDS scratch (C-layout), re-read as A fragments
#pragma unroll
      for (int nf = 0; nf < 4; ++nf)
#pragma unroll
        for (int r = 0; r < 4; ++r)
          pwv[(qrow0 + r) * 72 + nf * 16 + lrow] = f2bf_ru(sv[nf][r]);

      bf16x8 pa0 = *(const bf16x8*)&pwv[lrow * 72 + (l >> 4) * 8];
      bf16x8 pa1 = *(const bf16x8*)&pwv[lrow * 72 + 32 + (l >> 4) * 8];
      __builtin_amdgcn_s_setprio(1);
#pragma unroll
      for (int df = 0; df < 4; ++df) {
        const u16* vb2 = &v_lds[(df * 16 + lrow) * 64];
        bf16x8 v0 = *(const bf16x8*)(vb2 + c0s);
        bf16x8 v1 = *(const bf16x8*)(vb2 + c1s);
        o[df] = mfma16(pa0, v0, o[df]);
        o[df] = mfma16(pa1, v1, o[df]);
      }
      __builtin_amdgcn_s_setprio(0);
    }
  }

  // final denominator reduce over the 16-lane col groups
#pragma unroll
  for (int r = 0; r < 4; ++r) {
#pragma unroll
    for (int off = 1; off < 16; off <<= 1) lrun[r] += __shfl_xor(lrun[r], off, 64);
    lrun[r] = 1.f / lrun[r];
  }
#pragma unroll
  for (int df = 0; df < 4; ++df)
#pragma unroll
    for (int r = 0; r < 4; ++r) {
      int qq = q0 + w * 16 + (l >> 4) * 4 + r;
      int dk = df * 16 + (l & 15);
      float val = o[df][r] * lrun[r];
      ao[((size_t)b * T_ + qq) * D_ + h * DK_ + dk] = f2bf(val);
    }
}

extern "C" void kernel_launch(void* const* d_in, const int* in_sizes, int n_in,
                              void* d_out, int out_size, void* d_ws, size_t ws_size,
                              hipStream_t stream) {
  const float* inputs = (const float*)d_in[0];
  const float* ln1_g = (const float*)d_in[1];
  const float* ln1_b = (const float*)d_in[2];
  const float* ln2_g = (const float*)d_in[3];
  const float* ln2_b = (const float*)d_in[4];
  const float* W_qkv = (const float*)d_in[5];
  const float* W_pos = (const float*)d_in[6];
  const float* W_out = (const float*)d_in[7];
  const float* b_out = (const float*)d_in[8];
  const float* pbu = (const float*)d_in[9];
  const float* pbv = (const float*)d_in[10];
  float* out = (float*)d_out;

  char* ws = (char*)d_ws;
  size_t off = 0;
  auto alloc = [&](size_t bytes) {
    char* p = ws + off;
    off += (bytes + 255) & ~(size_t)255;
    return p;
  };
  u16* xn   = (u16*)alloc((size_t)M_ * D_ * 2);
  u16* wqkv = (u16*)alloc((size_t)3 * D_ * D_ * 2);
  u16* wpos = (u16*)alloc((size_t)D_ * D_ * 2);
  u16* wout = (u16*)alloc((size_t)D_ * D_ * 2);
  u16* pemb = (u16*)alloc((size_t)T_ * D_ * 2);
  u16* qB   = (u16*)alloc((size_t)M_ * D_ * 2);
  u16* kbB  = (u16*)alloc((size_t)M_ * D_ * 2);
  u16* vtB  = (u16*)alloc((size_t)M_ * D_ * 2);
  u16* pbuf = (u16*)alloc((size_t)H_ * T_ * DK_ * 2);
  u16* aoB  = (u16*)alloc((size_t)M_ * D_ * 2);
  if (ws_size < off) return;

  prep_k<<<PREP_BLKS, 256, 0, stream>>>(W_qkv, W_pos, W_out, wqkv, wpos, wout,
                                        inputs, pemb, ln1_g, ln1_b, ln2_g, ln2_b, xn);
  gemm_k<1><<<dim3(T_ / 128, D_ / 128), 256, 0, stream>>>(
      pemb, wpos, T_, D_, D_, pbuf, nullptr, nullptr, nullptr, nullptr);
  gemm_k<0><<<dim3(M_ / 128, (3 * D_) / 128), 256, 0, stream>>>(
      xn, wqkv, M_, 3 * D_, D_, qB, kbB, vtB, nullptr, nullptr);
  attn_k<<<1024, 256, 0, stream>>>(qB, kbB, vtB, pbuf, pbu, pbv, aoB);
  gemm_k<2><<<dim3(M_ / 128, D_ / 128), 256, 0, stream>>>(
      aoB, wout, M_, D_, D_, nullptr, nullptr, nullptr, out, b_out);
}